// Round 7
// baseline (90.487 us; speedup 1.0000x reference)
//
#include <hip/hip_runtime.h>

// Chamfer reconstruction loss, B=16, P=Q=4096, 3-D points, via bf16 MFMA.
//
// R16: R15's verified one-matrix/two-reductions math (row-mins + col-mins
// of the single D[gen x gt] per batch; |q|^2 carried in-matrix via k8-15
// with a ones-line B), re-tiled for TLP: 4 col-slabs of 1024 targets
// (LDS ~23KB) x grid 1024 -> 4 blocks/CU, and 2 tiles/iter so only
// c0,c1+zc accumulators are live (~120 unified regs) -> 4 waves/SIMD,
// 16 waves/CU (was 2). R15's cycle model: per-iter critical path =
// MFMA issue + ~50cyc MFMA latency + serial min tail, ~70% stall at
// 2 waves/SIMD (VALUBusy 65 / MfmaUtil 15). More waves + shorter tail
// turn the same VALU work into a throughput-bound ~15-22us kernel.

#define NB 16
#define NP 4096
#define NT 1024          // gt cols staged per block (4 slabs)
#define THREADS 256
#define NROWST 65536     // 16 b * 4096 gen rows
#define INV128 0.0078125f   // gt normalize: c/128 - 1
#define FINF __int_as_float(0x7F800000)

typedef __attribute__((ext_vector_type(8)))  short bf16x8;
typedef __attribute__((ext_vector_type(16))) float f32x16;

__device__ __forceinline__ short bf16rne(float f) {
    unsigned u = __float_as_uint(f);
    return (short)((u + 0x7FFFu + ((u >> 16) & 1u)) >> 16);
}
__device__ __forceinline__ float bf2f(short s) {
    return __uint_as_float(((unsigned)(unsigned short)s) << 16);
}
__device__ __forceinline__ float fold16(const f32x16& c) {
    float a = fminf(fminf(c[0], c[1]),  fminf(c[2],  c[3]));
    float b = fminf(fminf(c[4], c[5]),  fminf(c[6],  c[7]));
    float d = fminf(fminf(c[8], c[9]),  fminf(c[10], c[11]));
    float e = fminf(fminf(c[12], c[13]), fminf(c[14], c[15]));
    return fminf(fminf(a, b), fminf(d, e));
}

// grid = 1024: b = bid>>6, rs = (bid>>2)&15, cs = bid&3.
// Block: gen rows [rs*256, +256) x gt cols [cs*1024, +1024) of batch b.
__global__ __launch_bounds__(THREADS) void chamfer_kernel(const float* __restrict__ gen,
                                                          const float* __restrict__ label,
                                                          float* __restrict__ rowws,
                                                          int* __restrict__ colws) {
    // 16KB pack + ones line + prefetch-overrun pad + 4KB col-min keys
    __shared__ short spack[NT * 8 + 1280];
    __shared__ int colmin[NT];

    const int bid  = blockIdx.x;
    const int b    = bid >> 6;
    const int rs   = (bid >> 2) & 15;
    const int cs   = bid & 3;
    const int tid  = threadIdx.x;
    const int lane = tid & 63;
    const int wave = tid >> 6;            // 0..3
    const int base  = b * NP;
    const int tbase = base + cs * NT;     // first staged gt point

    // ones line for high-half lanes: B k8-15 = {1,1,0,...} pairs with
    // A high-lane {q2h,q2l,0,...} to add |q|^2 into every element.
    if (tid < 8) spack[NT * 8 + tid] = (tid < 2) ? (short)0x3F80 : (short)0;

    #pragma unroll
    for (int k = 0; k < 4; ++k) colmin[tid + k * 256] = 0x7F800000;  // +inf key

    // ---- pack 1024 gt targets: [t_hi xyz, t_lo xyz, t2_hi, t2_lo] ----
    #pragma unroll 4
    for (int k = 0; k < 4; ++k) {
        int j = tid + k * 256;
        const float* row = label + (size_t)(tbase + j) * 5;
        float x = fmaf(row[1], INV128, -1.0f);
        float y = fmaf(row[2], INV128, -1.0f);
        float z = fmaf(row[3], INV128, -1.0f);
        float t2 = fmaf(x, x, fmaf(y, y, z * z));
        short xh = bf16rne(x), yh = bf16rne(y), zh = bf16rne(z);
        short xl = bf16rne(x - bf2f(xh));
        short yl = bf16rne(y - bf2f(yh));
        short zl = bf16rne(z - bf2f(zh));
        short th = bf16rne(t2);
        short tl = bf16rne(t2 - bf2f(th));
        bf16x8 v = {xh, yh, zh, xl, yl, zl, th, tl};
        *(bf16x8*)(spack + j * 8) = v;
    }
    __syncthreads();                      // spack + colmin ready

    const f32x16 zc = {};

    #pragma unroll 1
    for (int sub = 0; sub < 2; ++sub) {
        // ---- per-lane query (gen) fragment: rows = lane&31 ----
        const int qrow = base + rs * 256 + sub * 128 + wave * 32 + (lane & 31);
        const float* g = gen + (size_t)qrow * 3;
        float x = g[0], y = g[1], z = g[2];
        float q2 = fmaf(x, x, fmaf(y, y, z * z));
        bf16x8 afrag;
        if (lane < 32) {                  // k0-7: -2q twice + 1,1 for t2
            short ax = bf16rne(-2.0f * x), ay = bf16rne(-2.0f * y), az = bf16rne(-2.0f * z);
            const short one = 0x3F80;
            bf16x8 a = {ax, ay, az, ax, ay, az, one, one};
            afrag = a;
        } else {                          // k8-15: q2 hi/lo against B ones
            short qh = bf16rne(q2);
            short ql = bf16rne(q2 - bf2f(qh));
            bf16x8 a = {qh, ql, 0, 0, 0, 0, 0, 0};
            afrag = a;
        }

        float mn[16];
        #pragma unroll
        for (int r = 0; r < 16; ++r) mn[r] = FINF;

        // ---- stream 32 col-tiles, 2/iter, register double-buffered ----
        const short* ol = spack + NT * 8;     // ones line (high lanes)
        const short* p0 = (lane < 32) ? (spack + (lane & 31) * 8)       : ol;
        const short* p1 = (lane < 32) ? (spack + (lane & 31) * 8 + 256) : ol;
        const int step = (lane < 32) ? 512 : 0;   // 2 tiles = 64 cols * 8 shorts

        bf16x8 b0 = *(const bf16x8*)p0;
        bf16x8 b1 = *(const bf16x8*)p1;
        #pragma unroll 2
        for (int it = 0; it < 16; ++it) {
            p0 += step; p1 += step;
            bf16x8 n0 = *(const bf16x8*)p0;   // last iter: dead reads into pad
            bf16x8 n1 = *(const bf16x8*)p1;
            f32x16 c0 = __builtin_amdgcn_mfma_f32_32x32x16_bf16(afrag, b0, zc, 0, 0, 0);
            f32x16 c1 = __builtin_amdgcn_mfma_f32_32x32x16_bf16(afrag, b1, zc, 0, 0, 0);
            // row-mins (min over cols, per output row-class)
            #pragma unroll
            for (int r = 0; r < 16; ++r) {
                mn[r] = fminf(fminf(c0[r], c1[r]), mn[r]);
            }
            // col-mins (min over this wave's 32 rows, per col): fold 16
            // regs -> 1, then LDS atomicMin of float_as_int(d+1) — both
            // lane halves hit the same col (2-way, HW-serialized).
            const int cb = it * 64 + (lane & 31);
            atomicMin(&colmin[cb],       __float_as_int(fold16(c0) + 1.0f));
            atomicMin(&colmin[cb + 32],  __float_as_int(fold16(c1) + 1.0f));
            b0 = n0; b1 = n1;
        }

        // ---- fold 32 column-classes (butterfly within each 32-lane half) ----
        #pragma unroll
        for (int m = 1; m <= 16; m <<= 1) {
            #pragma unroll
            for (int r = 0; r < 16; ++r)
                mn[r] = fminf(mn[r], __shfl_xor(mn[r], m, 64));
        }

        // ---- write per-row min (mn already includes q2) ----
        // C/D layout: row = (r&3) + 8*(r>>2) + 4*(lane>>5), col = lane&31.
        const int h4 = (lane >> 5) * 4;
        const int c  = lane & 31;
        const int row = (c & 3) + 8 * (c >> 2) + h4;     // valid for c<16
        float v = mn[0];
        #pragma unroll
        for (int r = 1; r < 16; ++r) if (c == r) v = mn[r];  // cndmask chain
        if (c < 16)
            rowws[cs * NROWST + base + rs * 256 + sub * 128 + wave * 32 + row] = v;
    }

    __syncthreads();                      // all col atomics done
    const int cwbase = ((b * 4 + cs) * 16 + rs) * NT;
    #pragma unroll
    for (int k = 0; k < 4; ++k)
        colws[cwbase + tid + k * 256] = colmin[tid + k * 256];
}

// grid 512: bid<256 -> row-mins (min over 4 colslabs, already include q2);
//           bid>=256 -> col-mins (min over 16 rowslab int keys, decode).
__global__ __launch_bounds__(256) void combine_kernel(const float* __restrict__ rowws,
                                                      const int* __restrict__ colws,
                                                      float* __restrict__ partial2) {
    const int tid = threadIdx.x;
    const int bid = blockIdx.x;
    float s;
    if (bid < 256) {
        int row = bid * 256 + tid;        // 0..65535
        s = fminf(fminf(rowws[row],              rowws[NROWST + row]),
                  fminf(rowws[2 * NROWST + row], rowws[3 * NROWST + row]));
    } else {
        int gidx = (bid - 256) * 256 + tid;   // global gt col 0..65535
        // gidx = b*4096 + cs*1024 + off -> (b*4+cs) = gidx>>10, off = gidx&1023
        const int* cw = colws + (gidx >> 10) * (16 * NT) + (gidx & (NT - 1));
        int k = cw[0];
        #pragma unroll
        for (int r2 = 1; r2 < 16; ++r2) k = min(k, cw[r2 * NT]);
        s = __int_as_float(k) - 1.0f;     // undo the +1 positivity shift
    }
    #pragma unroll
    for (int off = 32; off > 0; off >>= 1) s += __shfl_down(s, off, 64);
    __shared__ float w4[4];
    if ((tid & 63) == 0) w4[tid >> 6] = s;
    __syncthreads();
    if (tid == 0) partial2[bid] = (w4[0] + w4[1]) + (w4[2] + w4[3]);
}

__global__ __launch_bounds__(256) void reduce_kernel(const float* __restrict__ partial,
                                                     float* __restrict__ out) {
    int i = threadIdx.x;
    float s = partial[i] + partial[i + 256];  // 512 partials
    #pragma unroll
    for (int off = 32; off > 0; off >>= 1) s += __shfl_down(s, off, 64);
    __shared__ float ws4[4];
    if ((i & 63) == 0) ws4[i >> 6] = s;
    __syncthreads();
    if (i == 0) out[0] = ((ws4[0] + ws4[1]) + (ws4[2] + ws4[3])) * (1.0f / 65536.0f);
}

extern "C" void kernel_launch(void* const* d_in, const int* in_sizes, int n_in,
                              void* d_out, int out_size, void* d_ws, size_t ws_size,
                              hipStream_t stream) {
    const float* gen   = (const float*)d_in[0];   // [B*P, 3] fp32
    // d_in[1] = batch_gen (int32) — unused: segments are contiguous equal-size
    const float* label = (const float*)d_in[2];   // [B*Q, 5] fp32
    float* rowws    = (float*)d_ws;               // 4*65536 floats  (1 MB)
    int*   colws    = (int*)d_ws + 4 * NROWST;    // 16b*4cs*16rs*1024 ints (4 MB)
    float* partial2 = (float*)d_ws + 4 * NROWST + NB * 4 * 16 * NT;  // 512 floats
    float* out = (float*)d_out;

    chamfer_kernel<<<1024, THREADS, 0, stream>>>(gen, label, rowws, colws);
    combine_kernel<<<512, 256, 0, stream>>>(rowws, colws, partial2);
    reduce_kernel<<<1, 256, 0, stream>>>(partial2, out);
}

// Round 8
// 83.197 us; speedup vs baseline: 1.0876x; 1.0876x over previous
//
#include <hip/hip_runtime.h>

// Chamfer reconstruction loss, B=16, P=Q=4096, 3-D points, via bf16 MFMA.
//
// R17: R15's verified one-matrix/two-reductions structure (row-mins +
// col-mins of one D[gen x gt] per batch; |q|^2 in-matrix via k8-15 and a
// ones-line B), with the MFMAs moved to INLINE ASM with "=&v" outputs.
//
// Why: R9-R16 are pinned at ~37us chamfer regardless of occupancy
// (2/3/4 blocks/CU all flat) -> fixed per-wave inst stream. VGPR_Count
// 76-88 proves the f32x16 accumulators+zc live in AGPRs; every min
// consuming two accumulator elements then needs v_accvgpr_read (two
// AGPR sources are illegal), ~32 hidden VALU inst/tile -> ~3x the min
// network, VALUBusy 60-67% @ MfmaUtil 15%. The asm "v" constraints pin
// C/D tuples in arch VGPRs: min3/fold run VGPR-only, zero move traffic.
// s_nop 7,7,3 inside the block covers the MFMA->VALU-read hazard (the
// compiler cannot see into asm to insert them). Earlyclobber outputs
// prevent input/output register aliasing within the 4-MFMA sequence.

#define NB 16
#define NP 4096
#define NT 2048          // gt cols staged per block (2 slabs)
#define THREADS 256
#define NROWST 65536     // 16 b * 4096 gen rows
#define INV128 0.0078125f   // gt normalize: c/128 - 1
#define FINF __int_as_float(0x7F800000)

typedef __attribute__((ext_vector_type(8)))  short bf16x8;
typedef __attribute__((ext_vector_type(16))) float f32x16;

__device__ __forceinline__ short bf16rne(float f) {
    unsigned u = __float_as_uint(f);
    return (short)((u + 0x7FFFu + ((u >> 16) & 1u)) >> 16);
}
__device__ __forceinline__ float bf2f(short s) {
    return __uint_as_float(((unsigned)(unsigned short)s) << 16);
}
__device__ __forceinline__ float fold16(const f32x16& c) {
    // min3-friendly 16->1 fold (all operands VGPR)
    float a = fminf(fminf(c[0],  c[1]),  c[2]);
    float b = fminf(fminf(c[3],  c[4]),  c[5]);
    float d = fminf(fminf(c[6],  c[7]),  c[8]);
    float e = fminf(fminf(c[9],  c[10]), c[11]);
    float f = fminf(fminf(c[12], c[13]), c[14]);
    float g = fminf(fminf(a, b), c[15]);
    float h = fminf(fminf(d, e), f);
    return fminf(g, h);
}

// grid = 512: b = bid>>5, rs = (bid>>1)&15, cs = bid&1.
// Block: gen rows [rs*256, +256) x gt cols [cs*2048, +2048) of batch b.
__global__ __launch_bounds__(THREADS) void chamfer_kernel(const float* __restrict__ gen,
                                                          const float* __restrict__ label,
                                                          float* __restrict__ rowws,
                                                          int* __restrict__ colws) {
    // 32KB pack + ones line + prefetch-overrun pad + 8KB col-min keys
    __shared__ short spack[NT * 8 + 1280];
    __shared__ int colmin[NT];

    const int bid  = blockIdx.x;
    const int b    = bid >> 5;
    const int rs   = (bid >> 1) & 15;
    const int cs   = bid & 1;
    const int tid  = threadIdx.x;
    const int lane = tid & 63;
    const int wave = tid >> 6;            // 0..3
    const int base  = b * NP;
    const int tbase = base + cs * NT;     // first staged gt point

    // ones line for high-half lanes: B k8-15 = {1,1,0,...} pairs with
    // A high-lane {q2h,q2l,0,...} to add |q|^2 into every element.
    if (tid < 8) spack[NT * 8 + tid] = (tid < 2) ? (short)0x3F80 : (short)0;

    #pragma unroll
    for (int k = 0; k < 8; ++k) colmin[tid + k * 256] = 0x7F800000;  // +inf key

    // ---- pack 2048 gt targets: [t_hi xyz, t_lo xyz, t2_hi, t2_lo] ----
    #pragma unroll 4
    for (int k = 0; k < 8; ++k) {
        int j = tid + k * 256;
        const float* row = label + (size_t)(tbase + j) * 5;
        float x = fmaf(row[1], INV128, -1.0f);
        float y = fmaf(row[2], INV128, -1.0f);
        float z = fmaf(row[3], INV128, -1.0f);
        float t2 = fmaf(x, x, fmaf(y, y, z * z));
        short xh = bf16rne(x), yh = bf16rne(y), zh = bf16rne(z);
        short xl = bf16rne(x - bf2f(xh));
        short yl = bf16rne(y - bf2f(yh));
        short zl = bf16rne(z - bf2f(zh));
        short th = bf16rne(t2);
        short tl = bf16rne(t2 - bf2f(th));
        bf16x8 v = {xh, yh, zh, xl, yl, zl, th, tl};
        *(bf16x8*)(spack + j * 8) = v;
    }
    __syncthreads();                      // spack + colmin ready

    f32x16 zc = {};                       // persistent all-zero VGPR tuple

    #pragma unroll 1
    for (int sub = 0; sub < 2; ++sub) {
        // ---- per-lane query (gen) fragment: rows = lane&31 ----
        const int qrow = base + rs * 256 + sub * 128 + wave * 32 + (lane & 31);
        const float* g = gen + (size_t)qrow * 3;
        float x = g[0], y = g[1], z = g[2];
        float q2 = fmaf(x, x, fmaf(y, y, z * z));
        bf16x8 afrag;
        if (lane < 32) {                  // k0-7: -2q twice + 1,1 for t2
            short ax = bf16rne(-2.0f * x), ay = bf16rne(-2.0f * y), az = bf16rne(-2.0f * z);
            const short one = 0x3F80;
            bf16x8 a = {ax, ay, az, ax, ay, az, one, one};
            afrag = a;
        } else {                          // k8-15: q2 hi/lo against B ones
            short qh = bf16rne(q2);
            short ql = bf16rne(q2 - bf2f(qh));
            bf16x8 a = {qh, ql, 0, 0, 0, 0, 0, 0};
            afrag = a;
        }

        float mn[16];
        #pragma unroll
        for (int r = 0; r < 16; ++r) mn[r] = FINF;

        // ---- stream 64 col-tiles, 4/iter, register double-buffered ----
        const short* ol = spack + NT * 8;     // ones line (high lanes)
        const short* p0 = (lane < 32) ? (spack + (lane & 31) * 8)       : ol;
        const short* p1 = (lane < 32) ? (spack + (lane & 31) * 8 + 256) : ol;
        const short* p2 = (lane < 32) ? (spack + (lane & 31) * 8 + 512) : ol;
        const short* p3 = (lane < 32) ? (spack + (lane & 31) * 8 + 768) : ol;
        const int step = (lane < 32) ? 1024 : 0;   // 4 tiles = 128 cols * 8 shorts

        bf16x8 b0 = *(const bf16x8*)p0;
        bf16x8 b1 = *(const bf16x8*)p1;
        bf16x8 b2 = *(const bf16x8*)p2;
        bf16x8 b3 = *(const bf16x8*)p3;
        #pragma unroll 2
        for (int it = 0; it < 16; ++it) {
            p0 += step; p1 += step; p2 += step; p3 += step;
            bf16x8 n0 = *(const bf16x8*)p0;   // last iter: dead reads into pad
            bf16x8 n1 = *(const bf16x8*)p1;
            bf16x8 n2 = *(const bf16x8*)p2;
            bf16x8 n3 = *(const bf16x8*)p3;
            // 4 MFMAs with C/D pinned to arch VGPRs ("v"); earlyclobber
            // keeps outputs disjoint from inputs; s_nops cover the
            // MFMA->VALU-read hazard for the last result.
            f32x16 c0, c1, c2, c3;
            asm("v_mfma_f32_32x32x16_bf16 %0, %4, %5, %9\n\t"
                "v_mfma_f32_32x32x16_bf16 %1, %4, %6, %9\n\t"
                "v_mfma_f32_32x32x16_bf16 %2, %4, %7, %9\n\t"
                "v_mfma_f32_32x32x16_bf16 %3, %4, %8, %9\n\t"
                "s_nop 7\n\t"
                "s_nop 7\n\t"
                "s_nop 3"
                : "=&v"(c0), "=&v"(c1), "=&v"(c2), "=&v"(c3)
                : "v"(afrag), "v"(b0), "v"(b1), "v"(b2), "v"(b3), "v"(zc));
            // row-mins (min over cols, per output row-class) — 2 min3/r
            #pragma unroll
            for (int r = 0; r < 16; ++r) {
                mn[r] = fminf(fminf(c0[r], c1[r]), mn[r]);
                mn[r] = fminf(fminf(c2[r], c3[r]), mn[r]);
            }
            // col-mins (min over this wave's 32 rows, per col): fold 16
            // regs -> 1, then LDS atomicMin of float_as_int(d+1) — both
            // lane halves hit the same col (2-way, HW-serialized).
            const int cb = it * 128 + (lane & 31);
            atomicMin(&colmin[cb],       __float_as_int(fold16(c0) + 1.0f));
            atomicMin(&colmin[cb + 32],  __float_as_int(fold16(c1) + 1.0f));
            atomicMin(&colmin[cb + 64],  __float_as_int(fold16(c2) + 1.0f));
            atomicMin(&colmin[cb + 96],  __float_as_int(fold16(c3) + 1.0f));
            b0 = n0; b1 = n1; b2 = n2; b3 = n3;
        }

        // ---- fold 32 column-classes (butterfly within each 32-lane half) ----
        #pragma unroll
        for (int m = 1; m <= 16; m <<= 1) {
            #pragma unroll
            for (int r = 0; r < 16; ++r)
                mn[r] = fminf(mn[r], __shfl_xor(mn[r], m, 64));
        }

        // ---- write per-row min (mn already includes q2) ----
        // C/D layout: row = (r&3) + 8*(r>>2) + 4*(lane>>5), col = lane&31.
        const int h4 = (lane >> 5) * 4;
        const int c  = lane & 31;
        const int row = (c & 3) + 8 * (c >> 2) + h4;     // valid for c<16
        float v = mn[0];
        #pragma unroll
        for (int r = 1; r < 16; ++r) if (c == r) v = mn[r];  // cndmask chain
        if (c < 16)
            rowws[cs * NROWST + base + rs * 256 + sub * 128 + wave * 32 + row] = v;
    }

    __syncthreads();                      // all col atomics done
    const int cwbase = ((b * 2 + cs) * 16 + rs) * NT;
    #pragma unroll
    for (int k = 0; k < 8; ++k)
        colws[cwbase + tid + k * 256] = colmin[tid + k * 256];
}

// grid 512: bid<256 -> row-mins (min over 2 colslabs, already include q2);
//           bid>=256 -> col-mins (min over 16 rowslab int keys, decode).
__global__ __launch_bounds__(256) void combine_kernel(const float* __restrict__ rowws,
                                                      const int* __restrict__ colws,
                                                      float* __restrict__ partial2) {
    const int tid = threadIdx.x;
    const int bid = blockIdx.x;
    float s;
    if (bid < 256) {
        int row = bid * 256 + tid;        // 0..65535
        s = fminf(rowws[row], rowws[NROWST + row]);
    } else {
        int gidx = (bid - 256) * 256 + tid;   // global gt col 0..65535
        const int* cw = colws + (gidx >> 11) * (16 * NT) + (gidx & (NT - 1));
        int k = cw[0];
        #pragma unroll
        for (int r2 = 1; r2 < 16; ++r2) k = min(k, cw[r2 * NT]);
        s = __int_as_float(k) - 1.0f;     // undo the +1 positivity shift
    }
    #pragma unroll
    for (int off = 32; off > 0; off >>= 1) s += __shfl_down(s, off, 64);
    __shared__ float w4[4];
    if ((tid & 63) == 0) w4[tid >> 6] = s;
    __syncthreads();
    if (tid == 0) partial2[bid] = (w4[0] + w4[1]) + (w4[2] + w4[3]);
}

__global__ __launch_bounds__(256) void reduce_kernel(const float* __restrict__ partial,
                                                     float* __restrict__ out) {
    int i = threadIdx.x;
    float s = partial[i] + partial[i + 256];  // 512 partials
    #pragma unroll
    for (int off = 32; off > 0; off >>= 1) s += __shfl_down(s, off, 64);
    __shared__ float ws4[4];
    if ((i & 63) == 0) ws4[i >> 6] = s;
    __syncthreads();
    if (i == 0) out[0] = ((ws4[0] + ws4[1]) + (ws4[2] + ws4[3])) * (1.0f / 65536.0f);
}

extern "C" void kernel_launch(void* const* d_in, const int* in_sizes, int n_in,
                              void* d_out, int out_size, void* d_ws, size_t ws_size,
                              hipStream_t stream) {
    const float* gen   = (const float*)d_in[0];   // [B*P, 3] fp32
    // d_in[1] = batch_gen (int32) — unused: segments are contiguous equal-size
    const float* label = (const float*)d_in[2];   // [B*Q, 5] fp32
    float* rowws    = (float*)d_ws;               // 2*65536 floats  (512 KB)
    int*   colws    = (int*)d_ws + 2 * NROWST;    // 16b*2cs*16rs*2048 ints (4 MB)
    float* partial2 = (float*)d_ws + 2 * NROWST + NB * 2 * 16 * NT;  // 512 floats
    float* out = (float*)d_out;

    chamfer_kernel<<<512, THREADS, 0, stream>>>(gen, label, rowws, colws);
    combine_kernel<<<512, 256, 0, stream>>>(rowws, colws, partial2);
    reduce_kernel<<<1, 256, 0, stream>>>(partial2, out);
}

// Round 9
// 81.407 us; speedup vs baseline: 1.1115x; 1.0220x over previous
//
#include <hip/hip_runtime.h>

// Chamfer reconstruction loss, B=16, P=Q=4096, 3-D points, via bf16 MFMA.
//
// R18: R17 (asm-MFMA, one-matrix row+col mins) with the LDS stream
// rewritten from roving 64-bit C pointers to ONE 32-bit index into the
// __shared__ array with +256/+512/+768 folded into ds_read immediates.
// Theory: the ternary+phi pointer chain can defeat InferAddressSpaces,
// lowering the stream to flat_load (64-bit addr math, vmcnt+lgkmcnt,
// slow path) — which would explain the occupancy/work-shape-invariant
// ~4-5x gap over the instruction-count floor that survived R14-R17.
// Indexing directly off spack guarantees addrspace(3) ds_read_b128 and
// drops ~10 addressing VALU/iter. High lanes hold a fixed base at the
// ones-line region, which now has FOUR ones-lines (one per immediate).

#define NB 16
#define NP 4096
#define NT 2048          // gt cols staged per block (2 slabs)
#define THREADS 256
#define NROWST 65536     // 16 b * 4096 gen rows
#define INV128 0.0078125f   // gt normalize: c/128 - 1
#define FINF __int_as_float(0x7F800000)

typedef __attribute__((ext_vector_type(8)))  short bf16x8;
typedef __attribute__((ext_vector_type(16))) float f32x16;

__device__ __forceinline__ short bf16rne(float f) {
    unsigned u = __float_as_uint(f);
    return (short)((u + 0x7FFFu + ((u >> 16) & 1u)) >> 16);
}
__device__ __forceinline__ float bf2f(short s) {
    return __uint_as_float(((unsigned)(unsigned short)s) << 16);
}
__device__ __forceinline__ float fold16(const f32x16& c) {
    // min3-friendly 16->1 fold (all operands VGPR)
    float a = fminf(fminf(c[0],  c[1]),  c[2]);
    float b = fminf(fminf(c[3],  c[4]),  c[5]);
    float d = fminf(fminf(c[6],  c[7]),  c[8]);
    float e = fminf(fminf(c[9],  c[10]), c[11]);
    float f = fminf(fminf(c[12], c[13]), c[14]);
    float g = fminf(fminf(a, b), c[15]);
    float h = fminf(fminf(d, e), f);
    return fminf(g, h);
}

// grid = 512: b = bid>>5, rs = (bid>>1)&15, cs = bid&1.
// Block: gen rows [rs*256, +256) x gt cols [cs*2048, +2048) of batch b.
__global__ __launch_bounds__(THREADS) void chamfer_kernel(const float* __restrict__ gen,
                                                          const float* __restrict__ label,
                                                          float* __restrict__ rowws,
                                                          int* __restrict__ colws) {
    // 32KB pack + 4 ones-lines + prefetch-overrun pad + 8KB col-min keys
    __shared__ short spack[NT * 8 + 1280];
    __shared__ int colmin[NT];

    const int bid  = blockIdx.x;
    const int b    = bid >> 5;
    const int rs   = (bid >> 1) & 15;
    const int cs   = bid & 1;
    const int tid  = threadIdx.x;
    const int lane = tid & 63;
    const int wave = tid >> 6;            // 0..3
    const int base  = b * NP;
    const int tbase = base + cs * NT;     // first staged gt point

    // FOUR ones-lines at NT*8 + {0,256,512,768} shorts: the high-lane
    // fixed base reads these via the same +256/+512/+768 immediates as
    // the low-lane tile stream. Each line = {1,1,0,0,0,0,0,0} so B
    // k8-15 pairs with A high-lane {q2h,q2l,0,...} to add |q|^2.
    if (tid < 32)
        spack[NT * 8 + (tid >> 3) * 256 + (tid & 7)] =
            ((tid & 7) < 2) ? (short)0x3F80 : (short)0;

    #pragma unroll
    for (int k = 0; k < 8; ++k) colmin[tid + k * 256] = 0x7F800000;  // +inf key

    // ---- pack 2048 gt targets: [t_hi xyz, t_lo xyz, t2_hi, t2_lo] ----
    #pragma unroll 4
    for (int k = 0; k < 8; ++k) {
        int j = tid + k * 256;
        const float* row = label + (size_t)(tbase + j) * 5;
        float x = fmaf(row[1], INV128, -1.0f);
        float y = fmaf(row[2], INV128, -1.0f);
        float z = fmaf(row[3], INV128, -1.0f);
        float t2 = fmaf(x, x, fmaf(y, y, z * z));
        short xh = bf16rne(x), yh = bf16rne(y), zh = bf16rne(z);
        short xl = bf16rne(x - bf2f(xh));
        short yl = bf16rne(y - bf2f(yh));
        short zl = bf16rne(z - bf2f(zh));
        short th = bf16rne(t2);
        short tl = bf16rne(t2 - bf2f(th));
        bf16x8 v = {xh, yh, zh, xl, yl, zl, th, tl};
        *(bf16x8*)(spack + j * 8) = v;
    }
    __syncthreads();                      // spack + colmin ready

    f32x16 zc = {};                       // persistent all-zero VGPR tuple

    #pragma unroll 1
    for (int sub = 0; sub < 2; ++sub) {
        // ---- per-lane query (gen) fragment: rows = lane&31 ----
        const int qrow = base + rs * 256 + sub * 128 + wave * 32 + (lane & 31);
        const float* g = gen + (size_t)qrow * 3;
        float x = g[0], y = g[1], z = g[2];
        float q2 = fmaf(x, x, fmaf(y, y, z * z));
        bf16x8 afrag;
        if (lane < 32) {                  // k0-7: -2q twice + 1,1 for t2
            short ax = bf16rne(-2.0f * x), ay = bf16rne(-2.0f * y), az = bf16rne(-2.0f * z);
            const short one = 0x3F80;
            bf16x8 a = {ax, ay, az, ax, ay, az, one, one};
            afrag = a;
        } else {                          // k8-15: q2 hi/lo against B ones
            short qh = bf16rne(q2);
            short ql = bf16rne(q2 - bf2f(qh));
            bf16x8 a = {qh, ql, 0, 0, 0, 0, 0, 0};
            afrag = a;
        }

        float mn[16];
        #pragma unroll
        for (int r = 0; r < 16; ++r) mn[r] = FINF;

        // ---- stream 64 col-tiles, 4/iter: ONE 32-bit index, +256/512/768
        // folded into ds_read immediates; register double-buffered ----
        const int obase = (lane < 32) ? ((lane & 31) * 8) : (NT * 8);
        const int step  = (lane < 32) ? 1024 : 0;   // 4 tiles = 128 cols * 8 shorts
        int off = obase;

        bf16x8 b0 = *(const bf16x8*)(spack + off);
        bf16x8 b1 = *(const bf16x8*)(spack + off + 256);
        bf16x8 b2 = *(const bf16x8*)(spack + off + 512);
        bf16x8 b3 = *(const bf16x8*)(spack + off + 768);
        #pragma unroll 2
        for (int it = 0; it < 16; ++it) {
            off += step;
            bf16x8 n0 = *(const bf16x8*)(spack + off);        // last iter: dead
            bf16x8 n1 = *(const bf16x8*)(spack + off + 256);  //   reads into pad
            bf16x8 n2 = *(const bf16x8*)(spack + off + 512);
            bf16x8 n3 = *(const bf16x8*)(spack + off + 768);
            // 4 MFMAs with C/D pinned to arch VGPRs ("v"); earlyclobber
            // keeps outputs disjoint from inputs; s_nops cover the
            // MFMA->VALU-read hazard for the last result.
            f32x16 c0, c1, c2, c3;
            asm("v_mfma_f32_32x32x16_bf16 %0, %4, %5, %9\n\t"
                "v_mfma_f32_32x32x16_bf16 %1, %4, %6, %9\n\t"
                "v_mfma_f32_32x32x16_bf16 %2, %4, %7, %9\n\t"
                "v_mfma_f32_32x32x16_bf16 %3, %4, %8, %9\n\t"
                "s_nop 7\n\t"
                "s_nop 7\n\t"
                "s_nop 3"
                : "=&v"(c0), "=&v"(c1), "=&v"(c2), "=&v"(c3)
                : "v"(afrag), "v"(b0), "v"(b1), "v"(b2), "v"(b3), "v"(zc));
            // row-mins (min over cols, per output row-class) — 2 min3/r
            #pragma unroll
            for (int r = 0; r < 16; ++r) {
                mn[r] = fminf(fminf(c0[r], c1[r]), mn[r]);
                mn[r] = fminf(fminf(c2[r], c3[r]), mn[r]);
            }
            // col-mins (min over this wave's 32 rows, per col): fold 16
            // regs -> 1, then LDS atomicMin of float_as_int(d+1) — both
            // lane halves hit the same col (2-way, HW-serialized).
            const int cb = it * 128 + (lane & 31);
            atomicMin(&colmin[cb],       __float_as_int(fold16(c0) + 1.0f));
            atomicMin(&colmin[cb + 32],  __float_as_int(fold16(c1) + 1.0f));
            atomicMin(&colmin[cb + 64],  __float_as_int(fold16(c2) + 1.0f));
            atomicMin(&colmin[cb + 96],  __float_as_int(fold16(c3) + 1.0f));
            b0 = n0; b1 = n1; b2 = n2; b3 = n3;
        }

        // ---- fold 32 column-classes (butterfly within each 32-lane half) ----
        #pragma unroll
        for (int m = 1; m <= 16; m <<= 1) {
            #pragma unroll
            for (int r = 0; r < 16; ++r)
                mn[r] = fminf(mn[r], __shfl_xor(mn[r], m, 64));
        }

        // ---- write per-row min (mn already includes q2) ----
        // C/D layout: row = (r&3) + 8*(r>>2) + 4*(lane>>5), col = lane&31.
        const int h4 = (lane >> 5) * 4;
        const int c  = lane & 31;
        const int row = (c & 3) + 8 * (c >> 2) + h4;     // valid for c<16
        float v = mn[0];
        #pragma unroll
        for (int r = 1; r < 16; ++r) if (c == r) v = mn[r];  // cndmask chain
        if (c < 16)
            rowws[cs * NROWST + base + rs * 256 + sub * 128 + wave * 32 + row] = v;
    }

    __syncthreads();                      // all col atomics done
    const int cwbase = ((b * 2 + cs) * 16 + rs) * NT;
    #pragma unroll
    for (int k = 0; k < 8; ++k)
        colws[cwbase + tid + k * 256] = colmin[tid + k * 256];
}

// grid 512: bid<256 -> row-mins (min over 2 colslabs, already include q2);
//           bid>=256 -> col-mins (min over 16 rowslab int keys, decode).
__global__ __launch_bounds__(256) void combine_kernel(const float* __restrict__ rowws,
                                                      const int* __restrict__ colws,
                                                      float* __restrict__ partial2) {
    const int tid = threadIdx.x;
    const int bid = blockIdx.x;
    float s;
    if (bid < 256) {
        int row = bid * 256 + tid;        // 0..65535
        s = fminf(rowws[row], rowws[NROWST + row]);
    } else {
        int gidx = (bid - 256) * 256 + tid;   // global gt col 0..65535
        const int* cw = colws + (gidx >> 11) * (16 * NT) + (gidx & (NT - 1));
        int k = cw[0];
        #pragma unroll
        for (int r2 = 1; r2 < 16; ++r2) k = min(k, cw[r2 * NT]);
        s = __int_as_float(k) - 1.0f;     // undo the +1 positivity shift
    }
    #pragma unroll
    for (int off = 32; off > 0; off >>= 1) s += __shfl_down(s, off, 64);
    __shared__ float w4[4];
    if ((tid & 63) == 0) w4[tid >> 6] = s;
    __syncthreads();
    if (tid == 0) partial2[bid] = (w4[0] + w4[1]) + (w4[2] + w4[3]);
}

__global__ __launch_bounds__(256) void reduce_kernel(const float* __restrict__ partial,
                                                     float* __restrict__ out) {
    int i = threadIdx.x;
    float s = partial[i] + partial[i + 256];  // 512 partials
    #pragma unroll
    for (int off = 32; off > 0; off >>= 1) s += __shfl_down(s, off, 64);
    __shared__ float ws4[4];
    if ((i & 63) == 0) ws4[i >> 6] = s;
    __syncthreads();
    if (i == 0) out[0] = ((ws4[0] + ws4[1]) + (ws4[2] + ws4[3])) * (1.0f / 65536.0f);
}

extern "C" void kernel_launch(void* const* d_in, const int* in_sizes, int n_in,
                              void* d_out, int out_size, void* d_ws, size_t ws_size,
                              hipStream_t stream) {
    const float* gen   = (const float*)d_in[0];   // [B*P, 3] fp32
    // d_in[1] = batch_gen (int32) — unused: segments are contiguous equal-size
    const float* label = (const float*)d_in[2];   // [B*Q, 5] fp32
    float* rowws    = (float*)d_ws;               // 2*65536 floats  (512 KB)
    int*   colws    = (int*)d_ws + 2 * NROWST;    // 16b*2cs*16rs*2048 ints (4 MB)
    float* partial2 = (float*)d_ws + 2 * NROWST + NB * 2 * 16 * NT;  // 512 floats
    float* out = (float*)d_out;

    chamfer_kernel<<<512, THREADS, 0, stream>>>(gen, label, rowws, colws);
    combine_kernel<<<512, 256, 0, stream>>>(rowws, colws, partial2);
    reduce_kernel<<<1, 256, 0, stream>>>(partial2, out);
}